// Round 9
// baseline (161.925 us; speedup 1.0000x reference)
//
#include <hip/hip_runtime.h>
#include <hip/hip_bf16.h>

typedef __bf16  bf16x8 __attribute__((ext_vector_type(8)));
typedef float   f32x4  __attribute__((ext_vector_type(4)));

#define DEV __device__ __forceinline__

DEV ushort f2b(float f){
  union { float f; unsigned u; } c; c.f = f;
  unsigned u = c.u;
  unsigned r = (u + 0x7FFFu + ((u >> 16) & 1u)) >> 16;
  return (ushort)r;
}
DEV float b2f(ushort h){
  union { unsigned u; float f; } c; c.u = ((unsigned)h) << 16;
  return c.f;
}
DEV void gload_lds16(const void* g, void* l){
  __builtin_amdgcn_global_load_lds(
      (const __attribute__((address_space(1))) void*)g,
      (__attribute__((address_space(3))) void*)l,
      16, 0, 0);
}
DEV bf16x8 cvt8(float4 a0, float4 a1){
  bf16x8 t;
  t[0]=(__bf16)a0.x; t[1]=(__bf16)a0.y; t[2]=(__bf16)a0.z; t[3]=(__bf16)a0.w;
  t[4]=(__bf16)a1.x; t[5]=(__bf16)a1.y; t[6]=(__bf16)a1.z; t[7]=(__bf16)a1.w;
  return t;
}

// ------------ prep: W1 f32->bf16, conv_w cvt (plain), conv_b pad --------------
__global__ void prep(const float* __restrict__ W1, const float* __restrict__ CW,
                     const float* __restrict__ CB,
                     ushort* __restrict__ W1b, ushort* __restrict__ CWb,
                     float* __restrict__ CBp){
  int bid = blockIdx.x, tid = threadIdx.x;
  if(bid < 512){
    int i = bid * 256 + tid;          // float4 index, 131072 total
    float4 f = ((const float4*)W1)[i];
    ushort4 o; o.x = f2b(f.x); o.y = f2b(f.y); o.z = f2b(f.z); o.w = f2b(f.w);
    ((ushort4*)W1b)[i] = o;
  } else if(bid < 640){
    int i = (bid - 512) * 256 + tid;  // 0..32767 (64 rows x 512)
    CWb[i] = f2b(CW[i]);
  } else {
    if(tid < 128) CBp[tid] = (tid < 64) ? CB[tid] : 0.0f;
  }
}

// -- fc1sm v2: BARRIER-FREE fc1 GEMM (frags direct from L2/L3-resident X, W1b;
//    no LDS staging, no per-k-step syncthreads -> no vmcnt(0) drains), then
//    bias/relu/L2norm, XNT write + transposed-logits MFMA with IN-REGISTER
//    softmax (waves 0-3) concurrent with XNT pack (waves 4-7).
//    LDS: xnm[64][520] bf16 (~65KB, 16B-aligned rows, ~conflict-free) only.
__global__ __launch_bounds__(512) void fc1sm(
    const float* __restrict__ A, const ushort* __restrict__ B,
    const float* __restrict__ bias, const ushort* __restrict__ CWb,
    const float* __restrict__ CBp, ushort* __restrict__ XNT,
    ushort* __restrict__ AThi, ushort* __restrict__ ATlo)
{
  __shared__ __align__(16) ushort xnm[64 * 520];   // [n-row][h], stride 1040 B
  __shared__ float ssq_p[4][64];
  __shared__ float scale_s[64];
  const int tid = threadIdx.x, lane = tid & 63, wid = tid >> 6;
  const int bm0 = blockIdx.x * 64;
  const int wr = (wid >> 2) * 32;          // 0 / 32
  const int wc = (wid & 3) * 128;          // 0 / 128 / 256 / 384
  const int wcol = wid & 3;
  const int arow = lane & 15;
  const int g16  = lane >> 4;              // khalf / row-group, 0..3

  // per-thread fragment base pointers (loop-invariant)
  const float*  a0p = A + (size_t)(bm0 + wr + arow) * 1024;
  const float*  a1p = a0p + (size_t)16 * 1024;
  const ushort* bp[8];
  #pragma unroll
  for(int ni = 0; ni < 8; ni++)
    bp[ni] = B + (size_t)(wc + ni * 16 + arow) * 1024;

  f32x4 acc[2][8];
  #pragma unroll
  for(int i = 0; i < 2; i++)
    #pragma unroll
    for(int j = 0; j < 8; j++) acc[i][j] = (f32x4){0.f, 0.f, 0.f, 0.f};

  // ---- main loop: 32 k-steps, zero barriers, compiler-pipelined loads ----
  #pragma unroll 4
  for(int ks = 0; ks < 32; ++ks){
    const int ko = ks * 32 + g16 * 8;      // f32/bf16 element offset
    bf16x8 af[2], bfr[8];
    {
      float4 x0 = *(const float4*)(a0p + ko);
      float4 x1 = *(const float4*)(a0p + ko + 4);
      af[0] = cvt8(x0, x1);
      float4 y0 = *(const float4*)(a1p + ko);
      float4 y1 = *(const float4*)(a1p + ko + 4);
      af[1] = cvt8(y0, y1);
    }
    #pragma unroll
    for(int ni = 0; ni < 8; ni++)
      bfr[ni] = *(const bf16x8*)(bp[ni] + ko);
    #pragma unroll
    for(int mi = 0; mi < 2; mi++)
      #pragma unroll
      for(int ni = 0; ni < 8; ni++)
        acc[mi][ni] = __builtin_amdgcn_mfma_f32_16x16x32_bf16(af[mi], bfr[ni], acc[mi][ni], 0, 0, 0);
  }

  // ---- epilogue 1: bias + relu, per-row ssq, scale ----
  float bv[8];
  #pragma unroll
  for(int ni = 0; ni < 8; ni++) bv[ni] = bias[wc + ni * 16 + arow];
  float p[2][4];
  #pragma unroll
  for(int mi = 0; mi < 2; mi++)
    #pragma unroll
    for(int i = 0; i < 4; i++){
      float s = 0.f;
      #pragma unroll
      for(int ni = 0; ni < 8; ni++){
        float v = fmaxf(acc[mi][ni][i] + bv[ni], 0.f);
        acc[mi][ni][i] = v;
        s += v * v;
      }
      p[mi][i] = s;
    }
  #pragma unroll
  for(int o = 1; o < 16; o <<= 1)
    #pragma unroll
    for(int mi = 0; mi < 2; mi++)
      #pragma unroll
      for(int i = 0; i < 4; i++)
        p[mi][i] += __shfl_xor(p[mi][i], o, 64);
  if(arow == 0){
    #pragma unroll
    for(int mi = 0; mi < 2; mi++)
      #pragma unroll
      for(int i = 0; i < 4; i++)
        ssq_p[wcol][wr + mi * 16 + g16 * 4 + i] = p[mi][i];
  }
  __syncthreads();
  if(tid < 64){
    float s = ssq_p[0][tid] + ssq_p[1][tid] + ssq_p[2][tid] + ssq_p[3][tid];
    scale_s[tid] = 1.0f / fmaxf(sqrtf(s), 1e-12f);
  }
  __syncthreads();

  // ---- epilogue 2: scaled bf16 -> xnm[n][520] ----
  #pragma unroll
  for(int mi = 0; mi < 2; mi++)
    #pragma unroll
    for(int i = 0; i < 4; i++){
      int rt = wr + mi * 16 + g16 * 4 + i;
      float sc = scale_s[rt];
      #pragma unroll
      for(int ni = 0; ni < 8; ni++){
        int h = wc + ni * 16 + arow;
        xnm[rt * 520 + h] = f2b(acc[mi][ni][i] * sc);
      }
    }
  __syncthreads();

  const int bb = bm0 >> 10, n0b = bm0 & 1023;

  if(wid < 4){
    // ---- logits via TRANSPOSED mfma(CW, xn): D[k][n], wave t = n-cols t*16.. --
    const int t = wid, c = arow;
    f32x4 lg[4];
    #pragma unroll
    for(int kf = 0; kf < 4; kf++) lg[kf] = (f32x4){0.f,0.f,0.f,0.f};
    const ushort* cw0 = CWb + (size_t)c * 512 + g16 * 8;     // + kf*16*512 + s*32
    const char*   xb0 = (const char*)xnm + (t * 16 + c) * 1040 + g16 * 16;
    #pragma unroll
    for(int s = 0; s < 16; ++s){
      bf16x8 xb = *(const bf16x8*)(xb0 + s * 64);
      #pragma unroll
      for(int kf = 0; kf < 4; kf++){
        bf16x8 cwf = *(const bf16x8*)(cw0 + (size_t)kf * 16 * 512 + s * 32);
        lg[kf] = __builtin_amdgcn_mfma_f32_16x16x32_bf16(cwf, xb, lg[kf], 0, 0, 0);
      }
    }
    // bias + in-register softmax over k (16 per thread + cross-g16 shfl)
    float l[4][4];
    float m = -3.4e38f;
    #pragma unroll
    for(int kf = 0; kf < 4; kf++)
      #pragma unroll
      for(int i = 0; i < 4; i++){
        l[kf][i] = lg[kf][i] + CBp[kf * 16 + g16 * 4 + i];
        m = fmaxf(m, l[kf][i]);
      }
    m = fmaxf(m, __shfl_xor(m, 16, 64));
    m = fmaxf(m, __shfl_xor(m, 32, 64));
    float s = 0.f;
    #pragma unroll
    for(int kf = 0; kf < 4; kf++)
      #pragma unroll
      for(int i = 0; i < 4; i++){
        l[kf][i] = __expf(l[kf][i] - m);
        s += l[kf][i];
      }
    s += __shfl_xor(s, 16, 64);
    s += __shfl_xor(s, 32, 64);
    float inv = 1.0f / s;
    #pragma unroll
    for(int kf = 0; kf < 4; kf++)
      #pragma unroll
      for(int i = 0; i < 4; i++){
        float a = l[kf][i] * inv;
        ushort hi = f2b(a);
        float lo = a - b2f(hi);
        int k = kf * 16 + g16 * 4 + i;
        size_t idx = ((size_t)bb * 64 + k) * 1024 + n0b + t * 16 + c;
        AThi[idx] = hi;
        ATlo[idx] = f2b(lo);
      }
  } else {
    // ---- XNT pack (waves 4-7): rows h = tid-256 and +256 ----
    #pragma unroll
    for(int rep = 0; rep < 2; rep++){
      int h = (tid - 256) + rep * 256;
      unsigned tmp[32];
      #pragma unroll
      for(int j = 0; j < 32; j++){
        unsigned lo = xnm[(2 * j)     * 520 + h];
        unsigned hi = xnm[(2 * j + 1) * 520 + h];
        tmp[j] = lo | (hi << 16);
      }
      ushort* dst = XNT + ((size_t)bb * 512 + h) * 1024 + n0b;
      #pragma unroll
      for(int u = 0; u < 8; u++){
        uint4 w; w.x = tmp[u*4]; w.y = tmp[u*4+1]; w.z = tmp[u*4+2]; w.w = tmp[u*4+3];
        *(uint4*)(dst + u * 8) = w;
      }
    }
  }
}

// ---- vlad_mfma: vlad[b][k][h] = Sum_n a*xn via MFMA, + asum corr + intra-norm -
__global__ __launch_bounds__(512) void vlad_mfma(
    const ushort* __restrict__ AThi, const ushort* __restrict__ ATlo,
    const ushort* __restrict__ XNT, const float* __restrict__ cent,
    ushort* __restrict__ vlb, float* __restrict__ ssq)
{
  __shared__ __align__(16) ushort Ah[2][16 * 32];    // 2 x 1 KB
  __shared__ __align__(16) ushort Al[2][16 * 32];    // 2 x 1 KB
  __shared__ __align__(16) ushort Xs[2][512 * 32];   // 2 x 32 KB
  __shared__ float red[8][16];
  __shared__ float scale_s[16], ssqn_s[16];
  const int tid = threadIdx.x, lane = tid & 63, wid = tid >> 6;
  const int b = blockIdx.x, kg = blockIdx.y;
  const int k0 = kg * 16;
  const int hw = wid;                        // h-base = hw*64
  const int arow = lane & 15, khalf = lane >> 4;

  const int xslot = (tid & 3) ^ ((tid >> 3) & 3);
  const ushort* xg = XNT + ((size_t)b * 512 + (tid >> 2)) * 1024 + xslot * 8;
  const int aslot = (lane & 3) ^ ((lane >> 3) & 3);
  const ushort* ahg = AThi + ((size_t)b * 64 + k0 + (lane >> 2)) * 1024 + aslot * 8;
  const ushort* alg = ATlo + ((size_t)b * 64 + k0 + (lane >> 2)) * 1024 + aslot * 8;

  f32x4 acc[4];
  #pragma unroll
  for(int i = 0; i < 4; i++) acc[i] = (f32x4){0.f, 0.f, 0.f, 0.f};
  f32x4 asum = (f32x4){0.f, 0.f, 0.f, 0.f};
  bf16x8 ones;
  #pragma unroll
  for(int j = 0; j < 8; j++) ones[j] = (__bf16)1.0f;

#define STAGE_VL(buf, n0v) do { \
    char* xd = (char*)&Xs[buf][0] + tid * 16; \
    gload_lds16(xg + (n0v),                xd); \
    gload_lds16(xg + (n0v) + 128 * 1024,   xd + 8192); \
    gload_lds16(xg + (n0v) + 256 * 1024,   xd + 16384); \
    gload_lds16(xg + (n0v) + 384 * 1024,   xd + 24576); \
    if(wid == 0)      gload_lds16(ahg + (n0v), (char*)&Ah[buf][0] + lane * 16); \
    else if(wid == 1) gload_lds16(alg + (n0v), (char*)&Al[buf][0] + lane * 16); \
  } while(0)

  STAGE_VL(0, 0);
  __syncthreads();

  int cur = 0;
  for(int ks = 0; ks < 32; ++ks){
    if(ks + 1 < 32) STAGE_VL(cur ^ 1, (ks + 1) * 32);
    bf16x8 ah, al, bfr[4];
    {
      int sl = khalf ^ ((arow >> 1) & 3);
      ah = *(const bf16x8*)&Ah[cur][arow * 32 + sl * 8];
      al = *(const bf16x8*)&Al[cur][arow * 32 + sl * 8];
    }
    #pragma unroll
    for(int ni = 0; ni < 4; ni++){
      int r = hw * 64 + ni * 16 + arow;
      bfr[ni] = *(const bf16x8*)&Xs[cur][r * 32 + ((khalf ^ ((r >> 1) & 3)) * 8)];
    }
    asum = __builtin_amdgcn_mfma_f32_16x16x32_bf16(ah, ones, asum, 0, 0, 0);
    asum = __builtin_amdgcn_mfma_f32_16x16x32_bf16(al, ones, asum, 0, 0, 0);
    #pragma unroll
    for(int ni = 0; ni < 4; ni++){
      acc[ni] = __builtin_amdgcn_mfma_f32_16x16x32_bf16(ah, bfr[ni], acc[ni], 0, 0, 0);
      acc[ni] = __builtin_amdgcn_mfma_f32_16x16x32_bf16(al, bfr[ni], acc[ni], 0, 0, 0);
    }
    __syncthreads();
    cur ^= 1;
  }
#undef STAGE_VL

  float vl[4][4];
  #pragma unroll
  for(int ni = 0; ni < 4; ni++)
    #pragma unroll
    for(int i = 0; i < 4; i++){
      int r_ = (lane >> 4) * 4 + i;
      int h = hw * 64 + ni * 16 + (lane & 15);
      vl[ni][i] = acc[ni][i] - asum[i] * cent[(size_t)(k0 + r_) * 512 + h];
    }
  float sq[4];
  #pragma unroll
  for(int i = 0; i < 4; i++){
    float s = 0.f;
    #pragma unroll
    for(int ni = 0; ni < 4; ni++) s += vl[ni][i] * vl[ni][i];
    sq[i] = s;
  }
  #pragma unroll
  for(int o = 1; o < 16; o <<= 1)
    #pragma unroll
    for(int i = 0; i < 4; i++) sq[i] += __shfl_xor(sq[i], o, 64);
  if((lane & 15) == 0){
    #pragma unroll
    for(int i = 0; i < 4; i++) red[hw][(lane >> 4) * 4 + i] = sq[i];
  }
  __syncthreads();
  if(tid < 16){
    float s = 0.f;
    #pragma unroll
    for(int w = 0; w < 8; w++) s += red[w][tid];
    float sc = 1.0f / fmaxf(sqrtf(s), 1e-12f);
    scale_s[tid] = sc;
    ssqn_s[tid] = s * sc * sc;
  }
  __syncthreads();
  if(tid < 4)
    ssq[b * 16 + kg * 4 + tid] = ssqn_s[tid * 4] + ssqn_s[tid * 4 + 1]
                               + ssqn_s[tid * 4 + 2] + ssqn_s[tid * 4 + 3];
  #pragma unroll
  for(int ni = 0; ni < 4; ni++)
    #pragma unroll
    for(int i = 0; i < 4; i++){
      int r_ = (lane >> 4) * 4 + i;
      int h = hw * 64 + ni * 16 + (lane & 15);
      vlb[(size_t)b * 32768 + (size_t)(k0 + r_) * 512 + h] = f2b(vl[ni][i] * scale_s[r_]);
    }
}

// ------------- fc2 via MFMA, dbuf staging, K-split 128 (4 blocks/CU) -----------
__global__ __launch_bounds__(256) void fc2_mfma(const float* __restrict__ W,
                                                const ushort* __restrict__ vlb,
                                                float* __restrict__ part){
  __shared__ __align__(16) float Bs[2][128 * 32];   // 2 x 16 KB, XOR-swizzled
  const int tid = threadIdx.x, lane = tid & 63, wid = tid >> 6;
  const int c0 = blockIdx.x * 128;
  const int kc = blockIdx.y;                      // 128 chunks of 256 k
  const size_t kbase = (size_t)kc * 256;

  const int srow = tid >> 3;                     // 0..31
  const int seg  = tid & 7;                      // 16B slot
  f32x4 acc0 = (f32x4){0.f,0.f,0.f,0.f};
  f32x4 acc1 = (f32x4){0.f,0.f,0.f,0.f};

  const int arow = lane & 15;
  const int khalf = lane >> 4;
  const int cRow0 = wid * 32 + (lane & 15);
  const int cRow1 = cRow0 + 16;

  #pragma unroll
  for(int pass = 0; pass < 4; ++pass){
    int row = pass * 32 + srow;
    const char* src = (const char*)W + (size_t)(c0 + row) * 131072
                      + kbase * 4 + ((seg ^ (row & 7)) * 16);
    gload_lds16(src, (char*)&Bs[0][0] + row * 128 + seg * 16);
  }
  __syncthreads();

  int cur = 0;
  for(int ks = 0; ks < 8; ++ks){
    if(ks + 1 < 8){
      #pragma unroll
      for(int pass = 0; pass < 4; ++pass){
        int row = pass * 32 + srow;
        const char* src = (const char*)W + (size_t)(c0 + row) * 131072
                          + (kbase + (ks + 1) * 32) * 4 + ((seg ^ (row & 7)) * 16);
        gload_lds16(src, (char*)&Bs[cur ^ 1][0] + row * 128 + seg * 16);
      }
    }
    bf16x8 af = *(const bf16x8*)((const char*)vlb + (size_t)arow * 65536
                                 + (kbase + ks * 32 + khalf * 8) * 2);
    int t0 = khalf * 2;
    const char* bsc = (const char*)&Bs[cur][0];
    float4 b00 = *(const float4*)(bsc + cRow0 * 128 + ((t0     ^ (cRow0 & 7)) * 16));
    float4 b01 = *(const float4*)(bsc + cRow0 * 128 + (((t0+1) ^ (cRow0 & 7)) * 16));
    float4 b10 = *(const float4*)(bsc + cRow1 * 128 + ((t0     ^ (cRow1 & 7)) * 16));
    float4 b11 = *(const float4*)(bsc + cRow1 * 128 + (((t0+1) ^ (cRow1 & 7)) * 16));
    bf16x8 bf0 = cvt8(b00, b01);
    bf16x8 bf1 = cvt8(b10, b11);

    acc0 = __builtin_amdgcn_mfma_f32_16x16x32_bf16(af, bf0, acc0, 0, 0, 0);
    acc1 = __builtin_amdgcn_mfma_f32_16x16x32_bf16(af, bf1, acc1, 0, 0, 0);
    __syncthreads();
    cur ^= 1;
  }

  #pragma unroll
  for(int i = 0; i < 4; ++i){
    int b = (lane >> 4) * 4 + i;
    int d0 = c0 + wid * 32 + (lane & 15);
    part[((size_t)kc * 16 + b) * 1024 + d0]      = acc0[i];
    part[((size_t)kc * 16 + b) * 1024 + d0 + 16] = acc1[i];
  }
}

// ------------- final: 4-way k-split + LDS reduce (256 blocks) ------------------
__global__ __launch_bounds__(256) void fin(const float* __restrict__ part, const float* __restrict__ ssq,
                                           const float* __restrict__ b2, float* __restrict__ out){
  __shared__ float red[4][64];
  int lane = threadIdx.x & 63, wq = threadIdx.x >> 6;
  int o = blockIdx.x * 64 + lane;             // 0..16383
  int b = o >> 10, d = o & 1023;
  float s = 0;
  #pragma unroll
  for(int i = 0; i < 32; i++){
    int t = wq * 32 + i;
    s += part[((size_t)t * 16 + b) * 1024 + d];
  }
  red[wq][lane] = s;
  __syncthreads();
  if(wq == 0){
    float g = 0;
    #pragma unroll
    for(int kg = 0; kg < 16; kg++) g += ssq[b * 16 + kg];
    float gsv = 1.0f / fmaxf(sqrtf(g), 1e-12f);
    float tot = red[0][lane] + red[1][lane] + red[2][lane] + red[3][lane];
    out[o] = fmaxf(gsv * tot + b2[d], 0.0f);
  }
}

extern "C" void kernel_launch(void* const* d_in, const int* in_sizes, int n_in,
                              void* d_out, int out_size, void* d_ws, size_t ws_size,
                              hipStream_t stream){
  const float* X    = (const float*)d_in[0];
  const float* W1   = (const float*)d_in[1];
  const float* B1   = (const float*)d_in[2];
  const float* CW   = (const float*)d_in[3];
  const float* CB   = (const float*)d_in[4];
  const float* CENT = (const float*)d_in[5];
  const float* W2   = (const float*)d_in[6];
  const float* B2   = (const float*)d_in[7];
  float* out = (float*)d_out;
  char* ws = (char*)d_ws;

  ushort* W1b  = (ushort*)(ws + 0);            //  1,048,576
  ushort* CWb  = (ushort*)(ws + 1048576);      //     65,536
  float*  CBp  = (float*) (ws + 1114112);      //        512
  ushort* XNT  = (ushort*)(ws + 1114624);      // 16,777,216
  ushort* AThi = (ushort*)(ws + 17891840);     //  2,097,152
  ushort* ATlo = (ushort*)(ws + 19988992);     //  2,097,152
  ushort* VLb  = (ushort*)(ws + 22086144);     //  1,048,576
  float*  SSQ  = (float*) (ws + 23134720);     //      1,024
  float*  PART = (float*) (ws + 23135744);     //  8,388,608

  // prep: W1 cvt + conv_w cvt + conv_b pad
  prep<<<641, 256, 0, stream>>>(W1, CW, CB, W1b, CWb, CBp);
  // fused fc1 (barrier-free, register-direct) + norm -> XNT, logits+softmax -> AT
  fc1sm<<<256, 512, 0, stream>>>(X, W1b, B1, CWb, CBp, XNT, AThi, ATlo);
  // VLAD via MFMA (a = hi+lo, asum via ones-MFMA) + intra-norm -> VLb + SSQ
  vlad_mfma<<<dim3(16, 4), 512, 0, stream>>>(AThi, ATlo, XNT, CENT, VLb, SSQ);
  // fc2: MFMA, dbuf staging, K-split 128 -> 1024 blocks (4/CU)
  fc2_mfma<<<dim3(8, 128), 256, 0, stream>>>(W2, VLb, PART);
  // final: gscale folded in; 4-way k-split + LDS reduce
  fin<<<256, 256, 0, stream>>>(PART, SSQ, B2, out);
}

// Round 10
// 104.452 us; speedup vs baseline: 1.5502x; 1.5502x over previous
//
#include <hip/hip_runtime.h>
#include <hip/hip_bf16.h>

typedef __bf16  bf16x8 __attribute__((ext_vector_type(8)));
typedef float   f32x4  __attribute__((ext_vector_type(4)));

#define DEV __device__ __forceinline__

DEV ushort f2b(float f){
  union { float f; unsigned u; } c; c.f = f;
  unsigned u = c.u;
  unsigned r = (u + 0x7FFFu + ((u >> 16) & 1u)) >> 16;
  return (ushort)r;
}
DEV float b2f(ushort h){
  union { unsigned u; float f; } c; c.u = ((unsigned)h) << 16;
  return c.f;
}
DEV float wredsum(float v){
  #pragma unroll
  for(int o = 32; o > 0; o >>= 1) v += __shfl_xor(v, o, 64);
  return v;
}
DEV float wredmax(float v){
  #pragma unroll
  for(int o = 32; o > 0; o >>= 1) v = fmaxf(v, __shfl_xor(v, o, 64));
  return v;
}
DEV void gload_lds16(const void* g, void* l){
  __builtin_amdgcn_global_load_lds(
      (const __attribute__((address_space(1))) void*)g,
      (__attribute__((address_space(3))) void*)l,
      16, 0, 0);
}
DEV bf16x8 cvt8(float4 a0, float4 a1){
  bf16x8 t;
  t[0]=(__bf16)a0.x; t[1]=(__bf16)a0.y; t[2]=(__bf16)a0.z; t[3]=(__bf16)a0.w;
  t[4]=(__bf16)a1.x; t[5]=(__bf16)a1.y; t[6]=(__bf16)a1.z; t[7]=(__bf16)a1.w;
  return t;
}

// ------- prep: W1 f32->bf16, conv_w cvt + PRE-SWIZZLE (seg^=k&7), conv_b ------
__global__ void prep(const float* __restrict__ W1, const float* __restrict__ CW,
                     const float* __restrict__ CB,
                     ushort* __restrict__ W1b, ushort* __restrict__ CWb,
                     float* __restrict__ CBp){
  int bid = blockIdx.x, tid = threadIdx.x;
  if(bid < 512){
    int i = bid * 256 + tid;          // float4 index, 131072 total
    float4 f = ((const float4*)W1)[i];
    ushort4 o; o.x = f2b(f.x); o.y = f2b(f.y); o.z = f2b(f.z); o.w = f2b(f.w);
    ((ushort4*)W1b)[i] = o;
  } else if(bid < 640){
    int i = (bid - 512) * 256 + tid;  // 0..32767 (64 real rows only)
    int k = i >> 9, h = i & 511;
    int seg = h >> 3, pos = h & 7;    // low-3 seg bits XORed -> hits bank field
    CWb[(k << 9) + ((seg ^ (k & 7)) << 3) + pos] = f2b(CW[i]);
  } else {
    if(tid < 128) CBp[tid] = (tid < 64) ? CB[tid] : 0.0f;
  }
}

// -- fc1sm v3: LDS-staged fc1 GEMM (64x512) with 3-DEEP pipeline + COUNTED
//    vmcnt + raw barriers (T3/T4): stage loads stay in flight across barriers
//    instead of the syncthreads vmcnt(0) drain that serialized R8 (77us,
//    MfmaUtil 9%). Epilogue (norm, XNT, logits+softmax, AT hi/lo) unchanged.
// smem: staging A 3x8KB [0,24K) + B 3x32KB [24K,120K)
//       epi:  xnm [0,65K) | CWs [65K,129K) | Tb [81.9K,149.5K) | as_ [129K,145.2K)
__global__ __launch_bounds__(512) void fc1sm(
    const float* __restrict__ A, const ushort* __restrict__ B,
    const float* __restrict__ bias, const ushort* __restrict__ CWb,
    const float* __restrict__ CBp, ushort* __restrict__ XNT,
    ushort* __restrict__ AThi, ushort* __restrict__ ATlo)
{
  const int K = 1024;
  __shared__ __align__(16) char smem[149504];
  __shared__ float ssq_p[4][64];
  __shared__ float scale_s[64];
  const int tid = threadIdx.x, lane = tid & 63, wid = tid >> 6;
  const int bm0 = blockIdx.x * 64;
  const int wr = (wid >> 2) * 32;          // 0 / 32
  const int wc = (wid & 3) * 128;          // 0 / 128 / 256 / 384
  const int wcol = wid & 3;

  const int srow = tid >> 3;               // 0..63 (A staging)
  const int sseg = tid & 7;
  const char* asrc = (const char*)A + (size_t)(bm0 + srow) * 4096
                     + (sseg ^ (srow & 7)) * 16;
  const int bslot = (tid & 3) ^ ((tid >> 3) & 3);
  const ushort* bg = B + (size_t)(tid >> 2) * K + bslot * 8;

  f32x4 acc[2][8];
  #pragma unroll
  for(int i = 0; i < 2; i++)
    #pragma unroll
    for(int j = 0; j < 8; j++) acc[i][j] = (f32x4){0.f, 0.f, 0.f, 0.f};

  const int arow = lane & 15;
  const int khalf = lane >> 4;

  // 5 VMEM instrs per thread per stage (1 A + 4 B)
#define STAGE_F1N(buf, kb) do { \
    gload_lds16(asrc + (kb), smem + (buf) * 8192 + tid * 16); \
    const ushort* bs_ = bg + ((kb) >> 2); \
    char* bd_ = smem + 24576 + (buf) * 32768 + tid * 16; \
    gload_lds16(bs_,           bd_); \
    gload_lds16(bs_ + 128 * K, bd_ + 8192); \
    gload_lds16(bs_ + 256 * K, bd_ + 16384); \
    gload_lds16(bs_ + 384 * K, bd_ + 24576); \
  } while(0)

  STAGE_F1N(0, 0);
  STAGE_F1N(1, 128);

  #pragma unroll
  for(int ks = 0; ks < 32; ++ks){
    const int cur = ks % 3;
    if(ks + 2 < 32){
      STAGE_F1N((ks + 2) % 3, (ks + 2) * 128);
      asm volatile("s_waitcnt vmcnt(10)" ::: "memory");   // stage(ks) landed (2 in flight)
    } else if(ks + 1 < 32){
      asm volatile("s_waitcnt vmcnt(5)" ::: "memory");    // stage(ks) landed (1 in flight)
    } else {
      asm volatile("s_waitcnt vmcnt(0)" ::: "memory");    // final drain
    }
    __builtin_amdgcn_s_barrier();            // all waves' stage(ks) visible
    __builtin_amdgcn_sched_barrier(0);       // pin frag reads below barrier
    bf16x8 af[2], bfr[8];
    #pragma unroll
    for(int mi = 0; mi < 2; mi++){
      int r = wr + mi * 16 + arow;
      const char* base = smem + cur * 8192 + r * 128;
      float4 a0 = *(const float4*)(base + (((khalf * 2)     ^ (r & 7)) * 16));
      float4 a1 = *(const float4*)(base + (((khalf * 2 + 1) ^ (r & 7)) * 16));
      af[mi] = cvt8(a0, a1);
    }
    #pragma unroll
    for(int ni = 0; ni < 8; ni++){
      int r = wc + ni * 16 + arow;
      bfr[ni] = *(const bf16x8*)(smem + 24576 + cur * 32768
                                 + r * 64 + ((khalf ^ ((r >> 1) & 3)) * 16));
    }
    #pragma unroll
    for(int mi = 0; mi < 2; mi++)
      #pragma unroll
      for(int ni = 0; ni < 8; ni++)
        acc[mi][ni] = __builtin_amdgcn_mfma_f32_16x16x32_bf16(af[mi], bfr[ni], acc[mi][ni], 0, 0, 0);
    __builtin_amdgcn_sched_barrier(0);       // pin frag reads above barrier
    __builtin_amdgcn_s_barrier();            // buf[cur] free for stage(ks+3)
  }
#undef STAGE_F1N

  // ---- epilogue 1: bias + relu, row ssq, scale ----
  float bv[8];
  #pragma unroll
  for(int ni = 0; ni < 8; ni++) bv[ni] = bias[wc + ni * 16 + (lane & 15)];
  float p[2][4];
  #pragma unroll
  for(int mi = 0; mi < 2; mi++)
    #pragma unroll
    for(int i = 0; i < 4; i++){
      float s = 0.f;
      #pragma unroll
      for(int ni = 0; ni < 8; ni++){
        float v = fmaxf(acc[mi][ni][i] + bv[ni], 0.f);
        acc[mi][ni][i] = v;
        s += v * v;
      }
      p[mi][i] = s;
    }
  #pragma unroll
  for(int o = 1; o < 16; o <<= 1)
    #pragma unroll
    for(int mi = 0; mi < 2; mi++)
      #pragma unroll
      for(int i = 0; i < 4; i++)
        p[mi][i] += __shfl_xor(p[mi][i], o, 64);
  if((lane & 15) == 0){
    int g = lane >> 4;
    #pragma unroll
    for(int mi = 0; mi < 2; mi++)
      #pragma unroll
      for(int i = 0; i < 4; i++)
        ssq_p[wcol][wr + mi * 16 + g * 4 + i] = p[mi][i];
  }
  __syncthreads();
  if(tid < 64){
    float s = ssq_p[0][tid] + ssq_p[1][tid] + ssq_p[2][tid] + ssq_p[3][tid];
    scale_s[tid] = 1.0f / fmaxf(sqrtf(s), 1e-12f);
  }
  __syncthreads();

  // ---- epilogue 2: scaled bf16 into Tb[h][66] (for XNT) + xn_nm[n][520] ----
  ushort* Tb  = (ushort*)(smem + 81920);
  ushort* xnm = (ushort*)smem;             // over dead staging
  #pragma unroll
  for(int mi = 0; mi < 2; mi++)
    #pragma unroll
    for(int i = 0; i < 4; i++){
      int rt = wr + mi * 16 + (lane >> 4) * 4 + i;
      float sc = scale_s[rt];
      #pragma unroll
      for(int ni = 0; ni < 8; ni++){
        int h = wc + ni * 16 + (lane & 15);
        ushort v = f2b(acc[mi][ni][i] * sc);
        Tb[h * 66 + rt] = v;
        xnm[rt * 520 + h] = v;
      }
    }
  __syncthreads();

  // ---- XNT[b][h][n0+0..63] from Tb ----
  const int bb = bm0 >> 10, n0b = bm0 & 1023;
  {
    const char* tb = (const char*)smem + 81920 + tid * 132;
    unsigned tmp[32];
    #pragma unroll
    for(int j = 0; j < 32; j++) tmp[j] = *(const unsigned*)(tb + j * 4);
    ushort* dst = XNT + ((size_t)bb * 512 + tid) * 1024 + n0b;
    #pragma unroll
    for(int u = 0; u < 8; u++){
      uint4 w; w.x = tmp[u*4]; w.y = tmp[u*4+1]; w.z = tmp[u*4+2]; w.w = tmp[u*4+3];
      *(uint4*)(dst + u * 8) = w;
    }
  }
  __syncthreads();

  // ---- stage CWs (64 rows x 512 h bf16, pre-swizzled source, linear copy) ----
  char* CWs = smem + 66560;                // over dead Tb
  #pragma unroll
  for(int pp = 0; pp < 8; pp++)
    gload_lds16((const char*)CWb + pp * 8192 + tid * 16, CWs + pp * 8192 + tid * 16);
  __syncthreads();

  // ---- logits MFMA: 64n x 64k, K=512h; wave tile 32n x 16k ----
  float* as_ = (float*)(smem + 132096);
  const int nt = (wid >> 2) * 32, kt = (wid & 3) * 16;
  f32x4 acc2[2];
  acc2[0] = (f32x4){0.f,0.f,0.f,0.f};
  acc2[1] = (f32x4){0.f,0.f,0.f,0.f};
  const int kr = kt + arow;
  #pragma unroll
  for(int s = 0; s < 16; ++s){
    bf16x8 a0 = *(const bf16x8*)(smem + (size_t)(nt + arow) * 1040 + s * 64 + khalf * 16);
    bf16x8 a1 = *(const bf16x8*)(smem + (size_t)(nt + 16 + arow) * 1040 + s * 64 + khalf * 16);
    bf16x8 bw = *(const bf16x8*)(CWs + kr * 1024 + (((s * 4 + khalf) ^ (kr & 7)) * 16));
    acc2[0] = __builtin_amdgcn_mfma_f32_16x16x32_bf16(a0, bw, acc2[0], 0, 0, 0);
    acc2[1] = __builtin_amdgcn_mfma_f32_16x16x32_bf16(a1, bw, acc2[1], 0, 0, 0);
  }
  {
    float bv2 = CBp[kt + (lane & 15)];
    #pragma unroll
    for(int mi = 0; mi < 2; mi++)
      #pragma unroll
      for(int i = 0; i < 4; i++)
        as_[(nt + mi * 16 + (lane >> 4) * 4 + i) * 65 + kt + (lane & 15)] = acc2[mi][i] + bv2;
  }
  __syncthreads();

  // ---- softmax over k=64 (8 waves x 8 rows, full-wave reduce) ----
  #pragma unroll
  for(int i = 0; i < 8; i++){
    int rl = wid * 8 + i;
    float l = as_[rl * 65 + lane];
    float m = wredmax(l);
    float e = __expf(l - m);
    float s = wredsum(e);
    as_[rl * 65 + lane] = e / s;
  }
  __syncthreads();

  // ---- hi/lo transposed write: AT*[b][k][n0+nl] ----
  {
    const int nl = tid & 63, kq = tid >> 6;
    #pragma unroll
    for(int q = 0; q < 8; q++){
      int k = kq * 8 + q;
      float a = as_[nl * 65 + k];
      ushort hi = f2b(a);
      float lo = a - b2f(hi);
      size_t idx = ((size_t)bb * 64 + k) * 1024 + n0b + nl;
      AThi[idx] = hi;
      ATlo[idx] = f2b(lo);
    }
  }
}

// ---- vlad_mfma: vlad[b][k][h] = Sum_n a*xn via MFMA, + asum corr + intra-norm -
__global__ __launch_bounds__(512) void vlad_mfma(
    const ushort* __restrict__ AThi, const ushort* __restrict__ ATlo,
    const ushort* __restrict__ XNT, const float* __restrict__ cent,
    ushort* __restrict__ vlb, float* __restrict__ ssq)
{
  __shared__ __align__(16) ushort Ah[2][16 * 32];    // 2 x 1 KB
  __shared__ __align__(16) ushort Al[2][16 * 32];    // 2 x 1 KB
  __shared__ __align__(16) ushort Xs[2][512 * 32];   // 2 x 32 KB
  __shared__ float red[8][16];
  __shared__ float scale_s[16], ssqn_s[16];
  const int tid = threadIdx.x, lane = tid & 63, wid = tid >> 6;
  const int b = blockIdx.x, kg = blockIdx.y;
  const int k0 = kg * 16;
  const int hw = wid;                        // h-base = hw*64
  const int arow = lane & 15, khalf = lane >> 4;

  const int xslot = (tid & 3) ^ ((tid >> 3) & 3);
  const ushort* xg = XNT + ((size_t)b * 512 + (tid >> 2)) * 1024 + xslot * 8;
  const int aslot = (lane & 3) ^ ((lane >> 3) & 3);
  const ushort* ahg = AThi + ((size_t)b * 64 + k0 + (lane >> 2)) * 1024 + aslot * 8;
  const ushort* alg = ATlo + ((size_t)b * 64 + k0 + (lane >> 2)) * 1024 + aslot * 8;

  f32x4 acc[4];
  #pragma unroll
  for(int i = 0; i < 4; i++) acc[i] = (f32x4){0.f, 0.f, 0.f, 0.f};
  f32x4 asum = (f32x4){0.f, 0.f, 0.f, 0.f};
  bf16x8 ones;
  #pragma unroll
  for(int j = 0; j < 8; j++) ones[j] = (__bf16)1.0f;

#define STAGE_VL(buf, n0v) do { \
    char* xd = (char*)&Xs[buf][0] + tid * 16; \
    gload_lds16(xg + (n0v),                xd); \
    gload_lds16(xg + (n0v) + 128 * 1024,   xd + 8192); \
    gload_lds16(xg + (n0v) + 256 * 1024,   xd + 16384); \
    gload_lds16(xg + (n0v) + 384 * 1024,   xd + 24576); \
    if(wid == 0)      gload_lds16(ahg + (n0v), (char*)&Ah[buf][0] + lane * 16); \
    else if(wid == 1) gload_lds16(alg + (n0v), (char*)&Al[buf][0] + lane * 16); \
  } while(0)

  STAGE_VL(0, 0);
  __syncthreads();

  int cur = 0;
  for(int ks = 0; ks < 32; ++ks){
    if(ks + 1 < 32) STAGE_VL(cur ^ 1, (ks + 1) * 32);
    bf16x8 ah, al, bfr[4];
    {
      int sl = khalf ^ ((arow >> 1) & 3);
      ah = *(const bf16x8*)&Ah[cur][arow * 32 + sl * 8];
      al = *(const bf16x8*)&Al[cur][arow * 32 + sl * 8];
    }
    #pragma unroll
    for(int ni = 0; ni < 4; ni++){
      int r = hw * 64 + ni * 16 + arow;
      bfr[ni] = *(const bf16x8*)&Xs[cur][r * 32 + ((khalf ^ ((r >> 1) & 3)) * 8)];
    }
    asum = __builtin_amdgcn_mfma_f32_16x16x32_bf16(ah, ones, asum, 0, 0, 0);
    asum = __builtin_amdgcn_mfma_f32_16x16x32_bf16(al, ones, asum, 0, 0, 0);
    #pragma unroll
    for(int ni = 0; ni < 4; ni++){
      acc[ni] = __builtin_amdgcn_mfma_f32_16x16x32_bf16(ah, bfr[ni], acc[ni], 0, 0, 0);
      acc[ni] = __builtin_amdgcn_mfma_f32_16x16x32_bf16(al, bfr[ni], acc[ni], 0, 0, 0);
    }
    __syncthreads();
    cur ^= 1;
  }
#undef STAGE_VL

  float vl[4][4];
  #pragma unroll
  for(int ni = 0; ni < 4; ni++)
    #pragma unroll
    for(int i = 0; i < 4; i++){
      int r_ = (lane >> 4) * 4 + i;
      int h = hw * 64 + ni * 16 + (lane & 15);
      vl[ni][i] = acc[ni][i] - asum[i] * cent[(size_t)(k0 + r_) * 512 + h];
    }
  float sq[4];
  #pragma unroll
  for(int i = 0; i < 4; i++){
    float s = 0.f;
    #pragma unroll
    for(int ni = 0; ni < 4; ni++) s += vl[ni][i] * vl[ni][i];
    sq[i] = s;
  }
  #pragma unroll
  for(int o = 1; o < 16; o <<= 1)
    #pragma unroll
    for(int i = 0; i < 4; i++) sq[i] += __shfl_xor(sq[i], o, 64);
  if((lane & 15) == 0){
    #pragma unroll
    for(int i = 0; i < 4; i++) red[hw][(lane >> 4) * 4 + i] = sq[i];
  }
  __syncthreads();
  if(tid < 16){
    float s = 0.f;
    #pragma unroll
    for(int w = 0; w < 8; w++) s += red[w][tid];
    float sc = 1.0f / fmaxf(sqrtf(s), 1e-12f);
    scale_s[tid] = sc;
    ssqn_s[tid] = s * sc * sc;
  }
  __syncthreads();
  if(tid < 4)
    ssq[b * 16 + kg * 4 + tid] = ssqn_s[tid * 4] + ssqn_s[tid * 4 + 1]
                               + ssqn_s[tid * 4 + 2] + ssqn_s[tid * 4 + 3];
  #pragma unroll
  for(int ni = 0; ni < 4; ni++)
    #pragma unroll
    for(int i = 0; i < 4; i++){
      int r_ = (lane >> 4) * 4 + i;
      int h = hw * 64 + ni * 16 + (lane & 15);
      vlb[(size_t)b * 32768 + (size_t)(k0 + r_) * 512 + h] = f2b(vl[ni][i] * scale_s[r_]);
    }
}

// ------------- fc2 via MFMA, dbuf staging, K-split 128 (4 blocks/CU) -----------
__global__ __launch_bounds__(256) void fc2_mfma(const float* __restrict__ W,
                                                const ushort* __restrict__ vlb,
                                                float* __restrict__ part){
  __shared__ __align__(16) float Bs[2][128 * 32];   // 2 x 16 KB, XOR-swizzled
  const int tid = threadIdx.x, lane = tid & 63, wid = tid >> 6;
  const int c0 = blockIdx.x * 128;
  const int kc = blockIdx.y;                      // 128 chunks of 256 k
  const size_t kbase = (size_t)kc * 256;

  const int srow = tid >> 3;                     // 0..31
  const int seg  = tid & 7;                      // 16B slot
  f32x4 acc0 = (f32x4){0.f,0.f,0.f,0.f};
  f32x4 acc1 = (f32x4){0.f,0.f,0.f,0.f};

  const int arow = lane & 15;
  const int khalf = lane >> 4;
  const int cRow0 = wid * 32 + (lane & 15);
  const int cRow1 = cRow0 + 16;

  #pragma unroll
  for(int pass = 0; pass < 4; ++pass){
    int row = pass * 32 + srow;
    const char* src = (const char*)W + (size_t)(c0 + row) * 131072
                      + kbase * 4 + ((seg ^ (row & 7)) * 16);
    gload_lds16(src, (char*)&Bs[0][0] + row * 128 + seg * 16);
  }
  __syncthreads();

  int cur = 0;
  for(int ks = 0; ks < 8; ++ks){
    if(ks + 1 < 8){
      #pragma unroll
      for(int pass = 0; pass < 4; ++pass){
        int row = pass * 32 + srow;
        const char* src = (const char*)W + (size_t)(c0 + row) * 131072
                          + (kbase + (ks + 1) * 32) * 4 + ((seg ^ (row & 7)) * 16);
        gload_lds16(src, (char*)&Bs[cur ^ 1][0] + row * 128 + seg * 16);
      }
    }
    bf16x8 af = *(const bf16x8*)((const char*)vlb + (size_t)arow * 65536
                                 + (kbase + ks * 32 + khalf * 8) * 2);
    int t0 = khalf * 2;
    const char* bsc = (const char*)&Bs[cur][0];
    float4 b00 = *(const float4*)(bsc + cRow0 * 128 + ((t0     ^ (cRow0 & 7)) * 16));
    float4 b01 = *(const float4*)(bsc + cRow0 * 128 + (((t0+1) ^ (cRow0 & 7)) * 16));
    float4 b10 = *(const float4*)(bsc + cRow1 * 128 + ((t0     ^ (cRow1 & 7)) * 16));
    float4 b11 = *(const float4*)(bsc + cRow1 * 128 + (((t0+1) ^ (cRow1 & 7)) * 16));
    bf16x8 bf0 = cvt8(b00, b01);
    bf16x8 bf1 = cvt8(b10, b11);

    acc0 = __builtin_amdgcn_mfma_f32_16x16x32_bf16(af, bf0, acc0, 0, 0, 0);
    acc1 = __builtin_amdgcn_mfma_f32_16x16x32_bf16(af, bf1, acc1, 0, 0, 0);
    __syncthreads();
    cur ^= 1;
  }

  #pragma unroll
  for(int i = 0; i < 4; ++i){
    int b = (lane >> 4) * 4 + i;
    int d0 = c0 + wid * 32 + (lane & 15);
    part[((size_t)kc * 16 + b) * 1024 + d0]      = acc0[i];
    part[((size_t)kc * 16 + b) * 1024 + d0 + 16] = acc1[i];
  }
}

// ------------- final: 4-way k-split + LDS reduce (256 blocks) ------------------
__global__ __launch_bounds__(256) void fin(const float* __restrict__ part, const float* __restrict__ ssq,
                                           const float* __restrict__ b2, float* __restrict__ out){
  __shared__ float red[4][64];
  int lane = threadIdx.x & 63, wq = threadIdx.x >> 6;
  int o = blockIdx.x * 64 + lane;             // 0..16383
  int b = o >> 10, d = o & 1023;
  float s = 0;
  #pragma unroll
  for(int i = 0; i < 32; i++){
    int t = wq * 32 + i;
    s += part[((size_t)t * 16 + b) * 1024 + d];
  }
  red[wq][lane] = s;
  __syncthreads();
  if(wq == 0){
    float g = 0;
    #pragma unroll
    for(int kg = 0; kg < 16; kg++) g += ssq[b * 16 + kg];
    float gsv = 1.0f / fmaxf(sqrtf(g), 1e-12f);
    float tot = red[0][lane] + red[1][lane] + red[2][lane] + red[3][lane];
    out[o] = fmaxf(gsv * tot + b2[d], 0.0f);
  }
}

extern "C" void kernel_launch(void* const* d_in, const int* in_sizes, int n_in,
                              void* d_out, int out_size, void* d_ws, size_t ws_size,
                              hipStream_t stream){
  const float* X    = (const float*)d_in[0];
  const float* W1   = (const float*)d_in[1];
  const float* B1   = (const float*)d_in[2];
  const float* CW   = (const float*)d_in[3];
  const float* CB   = (const float*)d_in[4];
  const float* CENT = (const float*)d_in[5];
  const float* W2   = (const float*)d_in[6];
  const float* B2   = (const float*)d_in[7];
  float* out = (float*)d_out;
  char* ws = (char*)d_ws;

  ushort* W1b  = (ushort*)(ws + 0);            //  1,048,576
  ushort* CWb  = (ushort*)(ws + 1048576);      //     65,536 (pre-swizzled)
  float*  CBp  = (float*) (ws + 1114112);      //        512
  ushort* XNT  = (ushort*)(ws + 1114624);      // 16,777,216
  ushort* AThi = (ushort*)(ws + 17891840);     //  2,097,152
  ushort* ATlo = (ushort*)(ws + 19988992);     //  2,097,152
  ushort* VLb  = (ushort*)(ws + 22086144);     //  1,048,576
  float*  SSQ  = (float*) (ws + 23134720);     //      1,024
  float*  PART = (float*) (ws + 23135744);     //  8,388,608

  // prep: W1 cvt + conv_w cvt/pre-swizzle + conv_b pad
  prep<<<641, 256, 0, stream>>>(W1, CW, CB, W1b, CWb, CBp);
  // fused fc1 (3-deep counted-vmcnt pipeline) + norm -> XNT, logits+softmax -> AT
  fc1sm<<<256, 512, 0, stream>>>(X, W1b, B1, CWb, CBp, XNT, AThi, ATlo);
  // VLAD via MFMA (a = hi+lo, asum via ones-MFMA) + intra-norm -> VLb + SSQ
  vlad_mfma<<<dim3(16, 4), 512, 0, stream>>>(AThi, ATlo, XNT, CENT, VLb, SSQ);
  // fc2: MFMA, dbuf staging, K-split 128 -> 1024 blocks (4/CU)
  fc2_mfma<<<dim3(8, 128), 256, 0, stream>>>(W2, VLb, PART);
  // final: gscale folded in; 4-way k-split + LDS reduce
  fin<<<256, 256, 0, stream>>>(PART, SSQ, B2, out);
}